// Round 8
// baseline (481.973 us; speedup 1.0000x reference)
//
#include <hip/hip_runtime.h>
#include <stdint.h>

// ---------------------------------------------------------------------------
// Phased SNN:
//   0) input_kernel: simulate 544 input LIFs ONCE (1 block, 9 waves), store
//      per-step spike bitmasks (9 u64 words + zero pad) -> Sm[t][10]
//   1) hidden raster S: 512 blocks x 256thr; wave = (column, input-half).
//      s_in from mask bit (1 cndmask), tr_in rebuilt in-register; no input
//      LIF, no vi/cadd registers -> no pressure traffic. 1 barrier/step.
//   2) pack S bits + zero tail rows of Sf
//   3) Gram G = S S^T (popcount, exact)
//   4) M_T via wave-parallel decay scans
//   5) A_T = (S @ w2_0)^T f32 GEMM (K-split x2)
//   6) output LIF: per-64-chunk LDS-staged M tile + batched cross-chunk GEMV
// Valid because w2 is never clipped -> its evolution is linear in spikes.
// ---------------------------------------------------------------------------

#define DECAY_V  0.90483741803595952f   // exp(-1/10)
#define DECAY_TR 0.95122942450071403f   // exp(-1/20)
#define REST_F   (-70.0f)
#define RESET_F  (-65.0f)
#define THRESH_F (-55.0f)
#define ALPHA_F  (0.95f)
#define BETA_F   (0.8f)
#define NU1_PRE_F  (0.001f)
#define NU1_POST_F (0.01f)
#define NU2_F      (0.0001f)
#define GAIN_F     (20.0f)
#define LOG2D    (-0.072134752044448170f)  // log2(exp(-1/20))

static constexpr int IN_D  = 544;
static constexpr int HID_D = 1024;
static constexpr int OUT_D = 2048;
static constexpr int TMAX  = 512;

#define DP1  0.95122942450071403f
#define DP2  0.90483741803595957f
#define DP4  0.81873075307798186f
#define DP8  0.67032004603563930f
#define DP16 0.44932896411722159f
#define DP32 0.20189651799465541f

__device__ __forceinline__ float rdlane(float x, int l) {
    return __builtin_bit_cast(float,
        __builtin_amdgcn_readlane(__builtin_bit_cast(int, x), l));
}

template <int CTRL>
__device__ __forceinline__ float dpp_add(float x) {
    int y = __builtin_amdgcn_update_dpp(0, __builtin_bit_cast(int, x),
                                        CTRL, 0xF, 0xF, true);
    return x + __builtin_bit_cast(float, y);
}

__device__ __forceinline__ float wave_sum64(float x) {
    x = dpp_add<0xB1>(x);   // quad_perm [1,0,3,2]
    x = dpp_add<0x4E>(x);   // quad_perm [2,3,0,1]
    x = dpp_add<0x114>(x);  // row_shr:4
    x = dpp_add<0x118>(x);  // row_shr:8
    x = dpp_add<0x142>(x);  // row_bcast:15
    x = dpp_add<0x143>(x);  // row_bcast:31
    return rdlane(x, 63);
}

// lane-mask -> 1.0f/0.0f in one VALU op (mask in SGPR pair)
__device__ __forceinline__ float mask_sel(uint64_t m) {
    float r;
    asm("v_cndmask_b32 %0, 0, 1.0, %1" : "=v"(r) : "s"(m));
    return r;
}

// ------------- Phase 0: input LIF once, spike masks per step ---------------
__global__ __launch_bounds__(576)
void input_kernel(const float* __restrict__ x, const int* __restrict__ Tp,
                  unsigned long long* __restrict__ Sm)
{
    const int T = Tp[0];
    const int tid = threadIdx.x, lane = tid & 63, wv = tid >> 6;  // 9 waves
    const bool ok = (tid < IN_D);
    // pad word 9 = 0 for the h1 realignment
    for (int t = tid; t < T; t += 576) Sm[(size_t)t * 10 + 9] = 0ULL;
    const float cadd = REST_F * (1.0f - DECAY_V) + (ok ? x[tid] * GAIN_F : -1000.0f);
    float v = REST_F;
    for (int t = 0; t < T; ++t) {
        const float vv = fmaf(DECAY_V, v, cadd);     // same fma as hidden r7
        const bool sp = (vv >= THRESH_F);
        const unsigned long long m = __ballot(sp);
        v = sp ? RESET_F : vv;
        if (lane == 0) Sm[(size_t)t * 10 + wv] = m;
    }
}

// -------- Phase 1: hidden raster, wave = (column, input-half) --------------
__global__ __launch_bounds__(256, 2)
void hidden_kernel(const unsigned long long* __restrict__ Sm,
                   const float* __restrict__ w1,
                   const int* __restrict__ Tp, float* __restrict__ Sf)
{
    const int T = Tp[0];
    const int tid = threadIdx.x, lane = tid & 63, wv = tid >> 6;
    const int cp = wv >> 1;                  // 0/1 -> column within block
    const int h  = wv & 1;                   // input half: [272h, 272h+272)
    const int hh = __builtin_amdgcn_readfirstlane(h);   // scalarize
    const int col = blockIdx.x * 2 + cp;
    __shared__ float part[2][4];             // [parity][wave]

    float w[5], tr[5];
    #pragma unroll
    for (int k = 0; k < 5; ++k) {
        const int o = 64 * k + lane;         // offset within the half
        const int i = 272 * h + o;
        w[k]  = (o < 272) ? w1[(size_t)i * HID_D + col] : 0.f;
        tr[k] = 0.f;
    }
    float v_h = 0.f, b_h = 0.f, tr_h = 0.f;  // duplicated across the 2 waves

    uint64_t Mc[5], Mn[5];
    auto ldm = [&](uint64_t (&M)[5], int t) {
        const unsigned long long* __restrict__ p = Sm + (size_t)t * 10;
        if (hh == 0) {
            M[0] = p[0]; M[1] = p[1]; M[2] = p[2]; M[3] = p[3];
            M[4] = p[4] & 0xFFFFull;
        } else {
            const uint64_t a = p[4], b = p[5], c = p[6], d = p[7],
                           e = p[8], f = p[9];
            M[0] = (a >> 16) | (b << 48);
            M[1] = (b >> 16) | (c << 48);
            M[2] = (c >> 16) | (d << 48);
            M[3] = (d >> 16) | (e << 48);
            M[4] = (e >> 16) | (f << 48);
        }
    };
    ldm(Mc, 0);

    for (int t = 0; t < T; ++t) {
        if (t + 1 < T) ldm(Mn, t + 1);
        float acc = 0.f, s[5];
        #pragma unroll
        for (int k = 0; k < 5; ++k) {
            s[k]  = mask_sel(Mc[k]);               // s_in from spike bit
            tr[k] = fmaxf(tr[k] * DECAY_TR, s[k]); // == sp?1:tr*d (tr<=1)
            acc   = fmaf(s[k], w[k], acc);
        }
        const float p = wave_sum64(acc);
        const int par = t & 1;
        if (lane == 0) part[par][wv] = p;
        __syncthreads();
        const float tot = p + part[par][wv ^ 1];   // commutative -> bitexact
        // hidden RUM (identical in both waves of the column)
        const float vh2 = fmaf(ALPHA_F, v_h, tot);
        const bool hp = (vh2 >= 1.0f + b_h);
        const float sh = hp ? 1.f : 0.f;
        v_h  = hp ? 0.f : vh2;
        b_h  = fmaf(BETA_F, b_h, sh);
        tr_h = hp ? 1.f : tr_h * DECAY_TR;
        // STDP on this wave's 272 weights
        const float apot = hp ? NU1_POST_F : 0.f;
        const float adep = NU1_PRE_F * tr_h;
        #pragma unroll
        for (int k = 0; k < 5; ++k) {
            const float a  = fmaf(apot, tr[k], w[k]);
            const float nw = fmaf(-adep, s[k], a);
            w[k] = __builtin_amdgcn_fmed3f(nw, 0.f, 1.f);
        }
        if (h == 0 && lane == 0) Sf[(size_t)t * HID_D + col] = sh;
        #pragma unroll
        for (int k = 0; k < 5; ++k) Mc[k] = Mn[k];
    }
}

// ---------------- Phase 2: bit-pack S (+ zero tail rows) -------------------
__global__ void pack_kernel(float* __restrict__ Sf, const int* __restrict__ Tp,
                            unsigned long long* __restrict__ Sb)
{
    const int T = Tp[0];
    const int t = blockIdx.x;
    const int lane = threadIdx.x & 63, wv = threadIdx.x >> 6;
    if (t >= T) {
        ((float4*)(Sf + (size_t)t * HID_D))[threadIdx.x] = make_float4(0.f, 0.f, 0.f, 0.f);
        return;
    }
    #pragma unroll
    for (int q = 0; q < 4; ++q) {
        const int word = wv * 4 + q;
        const float s = Sf[(size_t)t * HID_D + word * 64 + lane];
        const unsigned long long m = __ballot(s > 0.5f);
        if (lane == 0) Sb[(size_t)t * 16 + word] = m;
    }
}

// ------------------------- Phase 3: Gram G = S S^T -------------------------
__global__ void gram_kernel(const unsigned long long* __restrict__ Sb,
                            const int* __restrict__ Tp, float* __restrict__ G)
{
    const int T = Tp[0];
    if ((int)blockIdx.x > (int)blockIdx.y) return;
    const int tid = threadIdx.x;
    __shared__ unsigned long long tR[16][17], uR[16][17];
    {
        const int r = tid >> 4, w = tid & 15;
        const int trow = blockIdx.y * 16 + r, urow = blockIdx.x * 16 + r;
        tR[r][w] = (trow < T) ? Sb[(size_t)trow * 16 + w] : 0ULL;
        uR[r][w] = (urow < T) ? Sb[(size_t)urow * 16 + w] : 0ULL;
    }
    __syncthreads();
    const int tx = tid & 15, ty = tid >> 4;
    const int t = blockIdx.y * 16 + ty, u = blockIdx.x * 16 + tx;
    if (t < T && u < t) {
        int s = 0;
        #pragma unroll
        for (int w = 0; w < 16; ++w) s += __popcll(tR[ty][w] & uR[tx][w]);
        G[(size_t)t * TMAX + u] = (float)s;
    }
}

// -------------- Phase 4: M_T columns via parallel decay scans --------------
// Writes only MT[tau][t] for tau < t, t < T. Unwritten region is never read.
__global__ __launch_bounds__(256)
void mt_kernel(const float* __restrict__ G, const int* __restrict__ Tp,
               float* __restrict__ MT)
{
    const int T = Tp[0];
    const int lane = threadIdx.x & 63;
    const int t = blockIdx.x * 4 + (threadIdx.x >> 6);
    if (t >= T) return;
    const float* Gr = G + (size_t)t * TMAX;
    const float dl1  = exp2f((float)(lane + 1) * LOG2D);
    const float d64l = exp2f((float)(64 - lane) * LOG2D);

    float g[8], kk[8];
    #pragma unroll
    for (int c = 0; c < 8; ++c) {
        const int tau = 64 * c + lane;
        g[c] = (tau < t) ? Gr[tau] : 0.f;
    }
    float kc = 0.f;
    #pragma unroll
    for (int c = 7; c >= 0; --c) {
        float k = g[c], u;
        u = __shfl_down(k, 1, 64);  if (lane < 63) k = fmaf(DP1, u, k);
        u = __shfl_down(k, 2, 64);  if (lane < 62) k = fmaf(DP2, u, k);
        u = __shfl_down(k, 4, 64);  if (lane < 60) k = fmaf(DP4, u, k);
        u = __shfl_down(k, 8, 64);  if (lane < 56) k = fmaf(DP8, u, k);
        u = __shfl_down(k, 16, 64); if (lane < 48) k = fmaf(DP16, u, k);
        u = __shfl_down(k, 32, 64); if (lane < 32) k = fmaf(DP32, u, k);
        k = fmaf(d64l, kc, k);
        kk[c] = k;
        kc = rdlane(k, 0);
    }
    float hc = 0.f;
    #pragma unroll
    for (int c = 0; c < 8; ++c) {
        float h = g[c], u;
        u = __shfl_up(h, 1, 64);  if (lane >= 1)  h = fmaf(DP1, u, h);
        u = __shfl_up(h, 2, 64);  if (lane >= 2)  h = fmaf(DP2, u, h);
        u = __shfl_up(h, 4, 64);  if (lane >= 4)  h = fmaf(DP4, u, h);
        u = __shfl_up(h, 8, 64);  if (lane >= 8)  h = fmaf(DP8, u, h);
        u = __shfl_up(h, 16, 64); if (lane >= 16) h = fmaf(DP16, u, h);
        u = __shfl_up(h, 32, 64); if (lane >= 32) h = fmaf(DP32, u, h);
        h = fmaf(dl1, hc, h);
        const int tau = 64 * c + lane;
        if (tau < t) MT[(size_t)tau * TMAX + t] = NU2_F * (h - kk[c]);
        hc = rdlane(h, 63);
    }
}

// ---------------- Phase 5: A_T = (S @ w2)^T, K-split GEMM ------------------
__global__ __launch_bounds__(256)
void gemm_kernel(const float* __restrict__ Sf, const float* __restrict__ w2,
                 float* __restrict__ AT, int klen)
{
    const int j0 = blockIdx.x * 128;
    const int t0 = blockIdx.y * 64;
    const int kbase = blockIdx.z * 512;
    __shared__ float Ss[16][68];
    __shared__ float Ws[16][192];
    const int tid = threadIdx.x;
    const int sr = tid >> 2, sq = tid & 3;
    const int wq2 = tid & 31, wr2 = tid >> 5;
    const int wcol = (wq2 >> 1) * 12 + (wq2 & 1) * 4;
    const int tj = tid & 15, tt = tid >> 4;
    const int tjc = tj * 12;

    float acc[4][8];
    #pragma unroll
    for (int a = 0; a < 4; ++a)
        #pragma unroll
        for (int b = 0; b < 8; ++b) acc[a][b] = 0.f;

    for (int k0 = 0; k0 < klen; k0 += 16) {
        const float4 sv = *(const float4*)&Sf[(size_t)(t0 + sr) * HID_D + kbase + k0 + sq * 4];
        const float4 wa = *(const float4*)&w2[(size_t)(kbase + k0 + wr2) * OUT_D + j0 + wq2 * 4];
        const float4 wb = *(const float4*)&w2[(size_t)(kbase + k0 + wr2 + 8) * OUT_D + j0 + wq2 * 4];
        __syncthreads();
        Ss[sq * 4 + 0][sr] = sv.x;
        Ss[sq * 4 + 1][sr] = sv.y;
        Ss[sq * 4 + 2][sr] = sv.z;
        Ss[sq * 4 + 3][sr] = sv.w;
        *(float4*)&Ws[wr2][wcol] = wa;
        *(float4*)&Ws[wr2 + 8][wcol] = wb;
        __syncthreads();
        #pragma unroll
        for (int kk = 0; kk < 16; ++kk) {
            const float4 a4 = *(const float4*)&Ss[kk][tt * 4];
            const float4 b0 = *(const float4*)&Ws[kk][tjc];
            const float4 b1 = *(const float4*)&Ws[kk][tjc + 4];
            const float aa[4] = {a4.x, a4.y, a4.z, a4.w};
            const float bb[8] = {b0.x, b0.y, b0.z, b0.w, b1.x, b1.y, b1.z, b1.w};
            #pragma unroll
            for (int ti = 0; ti < 4; ++ti)
                #pragma unroll
                for (int jj = 0; jj < 8; ++jj)
                    acc[ti][jj] = fmaf(aa[ti], bb[jj], acc[ti][jj]);
        }
    }
    #pragma unroll
    for (int jj = 0; jj < 8; ++jj)
        *(float4*)&AT[(size_t)blockIdx.z * OUT_D * TMAX +
                      (size_t)(j0 + tj * 8 + jj) * TMAX + t0 + tt * 4] =
            make_float4(acc[0][jj], acc[1][jj], acc[2][jj], acc[3][jj]);
}

// -------------- Phase 6: output recurrence, chunked ------------------------
template <int C>
__device__ __forceinline__ void out_chunk(
    const float* __restrict__ AT, const float* __restrict__ MT,
    float (&hsA)[8], float (&hsB)[8], float& vA, float& vB,
    float* __restrict__ out, int j, int lane, int T, int nparts,
    float* __restrict__ LD, float2* __restrict__ so2)
{
    const int rem = T - 64 * C;
    const int mtv = (rem < 64) ? rem : 64;
    float avA = AT[(size_t)j * TMAX + 64 * C + lane];
    float avB = AT[(size_t)(j + 1) * TMAX + 64 * C + lane];
    if (nparts == 2) {
        avA += AT[(size_t)(OUT_D + j) * TMAX + 64 * C + lane];
        avB += AT[(size_t)(OUT_D + j + 1) * TMAX + 64 * C + lane];
    }
    const float* ldb = LD + (C & 1) * 4096;
    float accA = hsA[C], accB = hsB[C];
    float mv0 = ldb[lane];
    float mv1 = (mtv > 1) ? ldb[64 + lane] : 0.f;
    for (int tt = 0; tt < mtv; ++tt) {
        const float mv = mv0;
        mv0 = mv1;
        if (tt + 2 < mtv) mv1 = ldb[(tt + 2) * 64 + lane];
        const float ivA = rdlane(avA + accA, tt);
        const float ivB = rdlane(avB + accB, tt);
        const float vdA = fmaf(DECAY_V, vA, REST_F * (1.0f - DECAY_V)) + ivA;
        const float vdB = fmaf(DECAY_V, vB, REST_F * (1.0f - DECAY_V)) + ivB;
        const bool spA = (vdA >= THRESH_F);
        const bool spB = (vdB >= THRESH_F);
        const float soA = spA ? 1.f : 0.f;
        const float soB = spB ? 1.f : 0.f;
        vA = spA ? RESET_F : vdA;
        vB = spB ? RESET_F : vdB;
        if (lane == 0)
            *(float2*)&out[(size_t)(64 * C + tt) * OUT_D + j] = make_float2(soA, soB);
        if (lane == tt) so2[tt] = make_float2(soA, soB);
        accA = fmaf(soA, mv, accA);
        accB = fmaf(soB, mv, accB);
    }
    if (C + 1 < 8 && 64 * (C + 1) < T) {
        {
            float* dst = LD + ((C + 1) & 1) * 4096;
            const float* src = MT + (size_t)(64 * (C + 1)) * TMAX + 64 * (C + 1) + lane;
            #pragma unroll 16
            for (int r = 0; r < 64; ++r) {
                const float v = src[(size_t)r * TMAX];
                dst[r * 64 + lane] = (r < lane) ? v : 0.f;   // tau<t mask
            }
        }
        for (int tt = 0; tt < mtv; ++tt) {
            const float2 s = so2[tt];
            const float* Mrow = MT + (size_t)(64 * C + tt) * TMAX + lane;
            #pragma unroll
            for (int K = C + 1; K < 8; ++K) {
                const float mval = Mrow[64 * K];
                hsA[K] = fmaf(s.x, mval, hsA[K]);
                hsB[K] = fmaf(s.y, mval, hsB[K]);
            }
        }
    }
}

__global__ __launch_bounds__(64, 2)
void out_kernel(const float* __restrict__ AT, const float* __restrict__ MT,
                const int* __restrict__ Tp, float* __restrict__ out, int nparts)
{
    const int T = Tp[0];
    const int lane = threadIdx.x;
    const int j = blockIdx.x * 2;
    __shared__ float LD[2 * 4096];
    __shared__ float2 so2[64];

    float hsA[8], hsB[8];
    #pragma unroll
    for (int k = 0; k < 8; ++k) { hsA[k] = 0.f; hsB[k] = 0.f; }
    float vA = REST_F, vB = REST_F;

    {
        const float* src = MT + lane;
        #pragma unroll 16
        for (int r = 0; r < 64; ++r) {
            const float v = src[(size_t)r * TMAX];
            LD[r * 64 + lane] = (r < lane) ? v : 0.f;        // tau<t mask
        }
    }
    out_chunk<0>(AT, MT, hsA, hsB, vA, vB, out, j, lane, T, nparts, LD, so2);
    if (T >  64) out_chunk<1>(AT, MT, hsA, hsB, vA, vB, out, j, lane, T, nparts, LD, so2);
    if (T > 128) out_chunk<2>(AT, MT, hsA, hsB, vA, vB, out, j, lane, T, nparts, LD, so2);
    if (T > 192) out_chunk<3>(AT, MT, hsA, hsB, vA, vB, out, j, lane, T, nparts, LD, so2);
    if (T > 256) out_chunk<4>(AT, MT, hsA, hsB, vA, vB, out, j, lane, T, nparts, LD, so2);
    if (T > 320) out_chunk<5>(AT, MT, hsA, hsB, vA, vB, out, j, lane, T, nparts, LD, so2);
    if (T > 384) out_chunk<6>(AT, MT, hsA, hsB, vA, vB, out, j, lane, T, nparts, LD, so2);
    if (T > 448) out_chunk<7>(AT, MT, hsA, hsB, vA, vB, out, j, lane, T, nparts, LD, so2);
}

extern "C" void kernel_launch(void* const* d_in, const int* in_sizes, int n_in,
                              void* d_out, int out_size, void* d_ws, size_t ws_size,
                              hipStream_t stream) {
    const float* x  = (const float*)d_in[0];
    const float* w1 = (const float*)d_in[1];
    const float* w2 = (const float*)d_in[2];
    const int*   Tp = (const int*)d_in[3];
    float* out = (float*)d_out;
    char* ws = (char*)d_ws;
    // layout: Sm 64K | Sb 64K | G 1M | MT 1M | Sf 2M | AT 8M (K-split) or 4M
    unsigned long long* Sm = (unsigned long long*)(ws);
    unsigned long long* Sb = (unsigned long long*)(ws + 65536);
    float* G  = (float*)(ws + 131072);
    float* MT = (float*)(ws + 131072 + 1048576);
    float* Sf = (float*)(ws + 131072 + 2 * 1048576);
    float* AT = (float*)(ws + 131072 + 4 * 1048576);
    const size_t need2 = 131072 + 4 * 1048576 + 2 * 4194304;
    const int nparts = (ws_size >= need2) ? 2 : 1;
    const int klen = (nparts == 2) ? 512 : 1024;

    hipLaunchKernelGGL(input_kernel,  dim3(1), dim3(576), 0, stream, x, Tp, Sm);
    hipLaunchKernelGGL(hidden_kernel, dim3(HID_D / 2), dim3(256), 0, stream, Sm, w1, Tp, Sf);
    hipLaunchKernelGGL(pack_kernel,   dim3(TMAX), dim3(256), 0, stream, Sf, Tp, Sb);
    hipLaunchKernelGGL(gram_kernel,   dim3(32, 32), dim3(256), 0, stream, Sb, Tp, G);
    hipLaunchKernelGGL(mt_kernel,     dim3(128), dim3(256), 0, stream, G, Tp, MT);
    hipLaunchKernelGGL(gemm_kernel,   dim3(16, 8, nparts), dim3(256), 0, stream,
                       Sf, w2, AT, klen);
    hipLaunchKernelGGL(out_kernel,    dim3(OUT_D / 2), dim3(64), 0, stream, AT, MT, Tp, out, nparts);
}

// Round 9
// 369.101 us; speedup vs baseline: 1.3058x; 1.3058x over previous
//
#include <hip/hip_runtime.h>
#include <stdint.h>

// ---------------------------------------------------------------------------
// Phased SNN:
//   0) input_kernel: simulate 544 input LIFs ONCE (1 block), store spike
//      floats Sfin[t][544] (bit-identical fma/cmp to the hidden recompute)
//   1) hidden raster S: 512 blocks x 256thr; wave = (column, input-half).
//      s_in LOADED (coalesced, 1-step prefetch, L2-resident); tr_in rebuilt
//      in-register via fmaxf. 1 barrier/step, 2 waves/SIMD.
//   2) pack S bits + zero tail rows of Sf
//   3) Gram G = S S^T (popcount, exact)
//   4) M_T via wave-parallel decay scans
//   5) A_T = (S @ w2_0)^T f32 GEMM (K-split x2)
//   6) output LIF: per-64-chunk LDS-staged M tile + batched cross-chunk GEMV
// Valid because w2 is never clipped -> its evolution is linear in spikes.
// ---------------------------------------------------------------------------

#define DECAY_V  0.90483741803595952f   // exp(-1/10)
#define DECAY_TR 0.95122942450071403f   // exp(-1/20)
#define REST_F   (-70.0f)
#define RESET_F  (-65.0f)
#define THRESH_F (-55.0f)
#define ALPHA_F  (0.95f)
#define BETA_F   (0.8f)
#define NU1_PRE_F  (0.001f)
#define NU1_POST_F (0.01f)
#define NU2_F      (0.0001f)
#define GAIN_F     (20.0f)
#define LOG2D    (-0.072134752044448170f)  // log2(exp(-1/20))

static constexpr int IN_D  = 544;
static constexpr int HID_D = 1024;
static constexpr int OUT_D = 2048;
static constexpr int TMAX  = 512;

#define DP1  0.95122942450071403f
#define DP2  0.90483741803595957f
#define DP4  0.81873075307798186f
#define DP8  0.67032004603563930f
#define DP16 0.44932896411722159f
#define DP32 0.20189651799465541f

__device__ __forceinline__ float rdlane(float x, int l) {
    return __builtin_bit_cast(float,
        __builtin_amdgcn_readlane(__builtin_bit_cast(int, x), l));
}

template <int CTRL>
__device__ __forceinline__ float dpp_add(float x) {
    int y = __builtin_amdgcn_update_dpp(0, __builtin_bit_cast(int, x),
                                        CTRL, 0xF, 0xF, true);
    return x + __builtin_bit_cast(float, y);
}

__device__ __forceinline__ float wave_sum64(float x) {
    x = dpp_add<0xB1>(x);   // quad_perm [1,0,3,2]
    x = dpp_add<0x4E>(x);   // quad_perm [2,3,0,1]
    x = dpp_add<0x114>(x);  // row_shr:4
    x = dpp_add<0x118>(x);  // row_shr:8
    x = dpp_add<0x142>(x);  // row_bcast:15
    x = dpp_add<0x143>(x);  // row_bcast:31
    return rdlane(x, 63);
}

// ------------- Phase 0: input LIF once, spike floats per step --------------
__global__ __launch_bounds__(576)
void input_kernel(const float* __restrict__ x, const int* __restrict__ Tp,
                  float* __restrict__ Sfin)
{
    const int tid = threadIdx.x;
    if (tid >= IN_D) return;
    const int T = Tp[0];
    const float cadd = REST_F * (1.0f - DECAY_V) + x[tid] * GAIN_F;
    float v = REST_F;
    for (int t = 0; t < T; ++t) {
        const float vv = fmaf(DECAY_V, v, cadd);     // same fma as r7 hidden
        const bool sp = (vv >= THRESH_F);
        v = sp ? RESET_F : vv;
        Sfin[(size_t)t * IN_D + tid] = sp ? 1.f : 0.f;
    }
}

// -------- Phase 1: hidden raster, wave = (column, input-half) --------------
__global__ __launch_bounds__(256, 2)
void hidden_kernel(const float* __restrict__ Sfin, const float* __restrict__ w1,
                   const int* __restrict__ Tp, float* __restrict__ Sf)
{
    const int T = Tp[0];
    const int tid = threadIdx.x, lane = tid & 63, wv = tid >> 6;
    const int cp = wv >> 1;                  // 0/1 -> column within block
    const int h  = wv & 1;                   // input half: [272h, 272h+272)
    const int col = blockIdx.x * 2 + cp;
    __shared__ float part[2][4];             // [parity][wave]

    float w[5], tr[5];
    #pragma unroll
    for (int k = 0; k < 5; ++k) {
        const int o = 64 * k + lane;         // offset within the half
        const int i = 272 * h + o;
        w[k]  = (o < 272) ? w1[(size_t)i * HID_D + col] : 0.f;
        tr[k] = 0.f;
    }
    float v_h = 0.f, b_h = 0.f, tr_h = 0.f;  // duplicated across the 2 waves

    const float* __restrict__ srow = Sfin + 272 * h;
    float sc[5], sn[5];
    #pragma unroll
    for (int k = 0; k < 5; ++k) {
        const int o = 64 * k + lane;
        sc[k] = (o < 272) ? srow[o] : 0.f;            // step 0
    }

    for (int t = 0; t < T; ++t) {
        if (t + 1 < T) {                              // prefetch step t+1
            const float* __restrict__ p = srow + (size_t)(t + 1) * IN_D;
            #pragma unroll
            for (int k = 0; k < 5; ++k) {
                const int o = 64 * k + lane;
                sn[k] = (o < 272) ? p[o] : 0.f;
            }
        }
        float acc = 0.f;
        #pragma unroll
        for (int k = 0; k < 5; ++k) {
            tr[k] = fmaxf(tr[k] * DECAY_TR, sc[k]);   // == sp?1:tr*d (tr<=1)
            acc   = fmaf(sc[k], w[k], acc);
        }
        const float p = wave_sum64(acc);
        const int par = t & 1;
        if (lane == 0) part[par][wv] = p;
        __syncthreads();
        const float tot = p + part[par][wv ^ 1];      // commutative -> bitexact
        // hidden RUM (identical in both waves of the column)
        const float vh2 = fmaf(ALPHA_F, v_h, tot);
        const bool hp = (vh2 >= 1.0f + b_h);
        const float sh = hp ? 1.f : 0.f;
        v_h  = hp ? 0.f : vh2;
        b_h  = fmaf(BETA_F, b_h, sh);
        tr_h = hp ? 1.f : tr_h * DECAY_TR;
        // STDP on this wave's 272 weights
        const float apot = hp ? NU1_POST_F : 0.f;
        const float adep = NU1_PRE_F * tr_h;
        #pragma unroll
        for (int k = 0; k < 5; ++k) {
            const float a  = fmaf(apot, tr[k], w[k]);
            const float nw = fmaf(-adep, sc[k], a);
            w[k] = __builtin_amdgcn_fmed3f(nw, 0.f, 1.f);
        }
        if (h == 0 && lane == 0) Sf[(size_t)t * HID_D + col] = sh;
        #pragma unroll
        for (int k = 0; k < 5; ++k) sc[k] = sn[k];
    }
}

// ---------------- Phase 2: bit-pack S (+ zero tail rows) -------------------
__global__ void pack_kernel(float* __restrict__ Sf, const int* __restrict__ Tp,
                            unsigned long long* __restrict__ Sb)
{
    const int T = Tp[0];
    const int t = blockIdx.x;
    const int lane = threadIdx.x & 63, wv = threadIdx.x >> 6;
    if (t >= T) {
        ((float4*)(Sf + (size_t)t * HID_D))[threadIdx.x] = make_float4(0.f, 0.f, 0.f, 0.f);
        return;
    }
    #pragma unroll
    for (int q = 0; q < 4; ++q) {
        const int word = wv * 4 + q;
        const float s = Sf[(size_t)t * HID_D + word * 64 + lane];
        const unsigned long long m = __ballot(s > 0.5f);
        if (lane == 0) Sb[(size_t)t * 16 + word] = m;
    }
}

// ------------------------- Phase 3: Gram G = S S^T -------------------------
__global__ void gram_kernel(const unsigned long long* __restrict__ Sb,
                            const int* __restrict__ Tp, float* __restrict__ G)
{
    const int T = Tp[0];
    if ((int)blockIdx.x > (int)blockIdx.y) return;
    const int tid = threadIdx.x;
    __shared__ unsigned long long tR[16][17], uR[16][17];
    {
        const int r = tid >> 4, w = tid & 15;
        const int trow = blockIdx.y * 16 + r, urow = blockIdx.x * 16 + r;
        tR[r][w] = (trow < T) ? Sb[(size_t)trow * 16 + w] : 0ULL;
        uR[r][w] = (urow < T) ? Sb[(size_t)urow * 16 + w] : 0ULL;
    }
    __syncthreads();
    const int tx = tid & 15, ty = tid >> 4;
    const int t = blockIdx.y * 16 + ty, u = blockIdx.x * 16 + tx;
    if (t < T && u < t) {
        int s = 0;
        #pragma unroll
        for (int w = 0; w < 16; ++w) s += __popcll(tR[ty][w] & uR[tx][w]);
        G[(size_t)t * TMAX + u] = (float)s;
    }
}

// -------------- Phase 4: M_T columns via parallel decay scans --------------
// Writes only MT[tau][t] for tau < t, t < T. Unwritten region is never read.
__global__ __launch_bounds__(256)
void mt_kernel(const float* __restrict__ G, const int* __restrict__ Tp,
               float* __restrict__ MT)
{
    const int T = Tp[0];
    const int lane = threadIdx.x & 63;
    const int t = blockIdx.x * 4 + (threadIdx.x >> 6);
    if (t >= T) return;
    const float* Gr = G + (size_t)t * TMAX;
    const float dl1  = exp2f((float)(lane + 1) * LOG2D);
    const float d64l = exp2f((float)(64 - lane) * LOG2D);

    float g[8], kk[8];
    #pragma unroll
    for (int c = 0; c < 8; ++c) {
        const int tau = 64 * c + lane;
        g[c] = (tau < t) ? Gr[tau] : 0.f;
    }
    float kc = 0.f;
    #pragma unroll
    for (int c = 7; c >= 0; --c) {
        float k = g[c], u;
        u = __shfl_down(k, 1, 64);  if (lane < 63) k = fmaf(DP1, u, k);
        u = __shfl_down(k, 2, 64);  if (lane < 62) k = fmaf(DP2, u, k);
        u = __shfl_down(k, 4, 64);  if (lane < 60) k = fmaf(DP4, u, k);
        u = __shfl_down(k, 8, 64);  if (lane < 56) k = fmaf(DP8, u, k);
        u = __shfl_down(k, 16, 64); if (lane < 48) k = fmaf(DP16, u, k);
        u = __shfl_down(k, 32, 64); if (lane < 32) k = fmaf(DP32, u, k);
        k = fmaf(d64l, kc, k);
        kk[c] = k;
        kc = rdlane(k, 0);
    }
    float hc = 0.f;
    #pragma unroll
    for (int c = 0; c < 8; ++c) {
        float h = g[c], u;
        u = __shfl_up(h, 1, 64);  if (lane >= 1)  h = fmaf(DP1, u, h);
        u = __shfl_up(h, 2, 64);  if (lane >= 2)  h = fmaf(DP2, u, h);
        u = __shfl_up(h, 4, 64);  if (lane >= 4)  h = fmaf(DP4, u, h);
        u = __shfl_up(h, 8, 64);  if (lane >= 8)  h = fmaf(DP8, u, h);
        u = __shfl_up(h, 16, 64); if (lane >= 16) h = fmaf(DP16, u, h);
        u = __shfl_up(h, 32, 64); if (lane >= 32) h = fmaf(DP32, u, h);
        h = fmaf(dl1, hc, h);
        const int tau = 64 * c + lane;
        if (tau < t) MT[(size_t)tau * TMAX + t] = NU2_F * (h - kk[c]);
        hc = rdlane(h, 63);
    }
}

// ---------------- Phase 5: A_T = (S @ w2)^T, K-split GEMM ------------------
__global__ __launch_bounds__(256)
void gemm_kernel(const float* __restrict__ Sf, const float* __restrict__ w2,
                 float* __restrict__ AT, int klen)
{
    const int j0 = blockIdx.x * 128;
    const int t0 = blockIdx.y * 64;
    const int kbase = blockIdx.z * 512;
    __shared__ float Ss[16][68];
    __shared__ float Ws[16][192];
    const int tid = threadIdx.x;
    const int sr = tid >> 2, sq = tid & 3;
    const int wq2 = tid & 31, wr2 = tid >> 5;
    const int wcol = (wq2 >> 1) * 12 + (wq2 & 1) * 4;
    const int tj = tid & 15, tt = tid >> 4;
    const int tjc = tj * 12;

    float acc[4][8];
    #pragma unroll
    for (int a = 0; a < 4; ++a)
        #pragma unroll
        for (int b = 0; b < 8; ++b) acc[a][b] = 0.f;

    for (int k0 = 0; k0 < klen; k0 += 16) {
        const float4 sv = *(const float4*)&Sf[(size_t)(t0 + sr) * HID_D + kbase + k0 + sq * 4];
        const float4 wa = *(const float4*)&w2[(size_t)(kbase + k0 + wr2) * OUT_D + j0 + wq2 * 4];
        const float4 wb = *(const float4*)&w2[(size_t)(kbase + k0 + wr2 + 8) * OUT_D + j0 + wq2 * 4];
        __syncthreads();
        Ss[sq * 4 + 0][sr] = sv.x;
        Ss[sq * 4 + 1][sr] = sv.y;
        Ss[sq * 4 + 2][sr] = sv.z;
        Ss[sq * 4 + 3][sr] = sv.w;
        *(float4*)&Ws[wr2][wcol] = wa;
        *(float4*)&Ws[wr2 + 8][wcol] = wb;
        __syncthreads();
        #pragma unroll
        for (int kk = 0; kk < 16; ++kk) {
            const float4 a4 = *(const float4*)&Ss[kk][tt * 4];
            const float4 b0 = *(const float4*)&Ws[kk][tjc];
            const float4 b1 = *(const float4*)&Ws[kk][tjc + 4];
            const float aa[4] = {a4.x, a4.y, a4.z, a4.w};
            const float bb[8] = {b0.x, b0.y, b0.z, b0.w, b1.x, b1.y, b1.z, b1.w};
            #pragma unroll
            for (int ti = 0; ti < 4; ++ti)
                #pragma unroll
                for (int jj = 0; jj < 8; ++jj)
                    acc[ti][jj] = fmaf(aa[ti], bb[jj], acc[ti][jj]);
        }
    }
    #pragma unroll
    for (int jj = 0; jj < 8; ++jj)
        *(float4*)&AT[(size_t)blockIdx.z * OUT_D * TMAX +
                      (size_t)(j0 + tj * 8 + jj) * TMAX + t0 + tt * 4] =
            make_float4(acc[0][jj], acc[1][jj], acc[2][jj], acc[3][jj]);
}

// -------------- Phase 6: output recurrence, chunked ------------------------
template <int C>
__device__ __forceinline__ void out_chunk(
    const float* __restrict__ AT, const float* __restrict__ MT,
    float (&hsA)[8], float (&hsB)[8], float& vA, float& vB,
    float* __restrict__ out, int j, int lane, int T, int nparts,
    float* __restrict__ LD, float2* __restrict__ so2)
{
    const int rem = T - 64 * C;
    const int mtv = (rem < 64) ? rem : 64;
    float avA = AT[(size_t)j * TMAX + 64 * C + lane];
    float avB = AT[(size_t)(j + 1) * TMAX + 64 * C + lane];
    if (nparts == 2) {
        avA += AT[(size_t)(OUT_D + j) * TMAX + 64 * C + lane];
        avB += AT[(size_t)(OUT_D + j + 1) * TMAX + 64 * C + lane];
    }
    const float* ldb = LD + (C & 1) * 4096;
    float accA = hsA[C], accB = hsB[C];
    float mv0 = ldb[lane];
    float mv1 = (mtv > 1) ? ldb[64 + lane] : 0.f;
    for (int tt = 0; tt < mtv; ++tt) {
        const float mv = mv0;
        mv0 = mv1;
        if (tt + 2 < mtv) mv1 = ldb[(tt + 2) * 64 + lane];
        const float ivA = rdlane(avA + accA, tt);
        const float ivB = rdlane(avB + accB, tt);
        const float vdA = fmaf(DECAY_V, vA, REST_F * (1.0f - DECAY_V)) + ivA;
        const float vdB = fmaf(DECAY_V, vB, REST_F * (1.0f - DECAY_V)) + ivB;
        const bool spA = (vdA >= THRESH_F);
        const bool spB = (vdB >= THRESH_F);
        const float soA = spA ? 1.f : 0.f;
        const float soB = spB ? 1.f : 0.f;
        vA = spA ? RESET_F : vdA;
        vB = spB ? RESET_F : vdB;
        if (lane == 0)
            *(float2*)&out[(size_t)(64 * C + tt) * OUT_D + j] = make_float2(soA, soB);
        if (lane == tt) so2[tt] = make_float2(soA, soB);
        accA = fmaf(soA, mv, accA);
        accB = fmaf(soB, mv, accB);
    }
    if (C + 1 < 8 && 64 * (C + 1) < T) {
        {
            float* dst = LD + ((C + 1) & 1) * 4096;
            const float* src = MT + (size_t)(64 * (C + 1)) * TMAX + 64 * (C + 1) + lane;
            #pragma unroll 16
            for (int r = 0; r < 64; ++r) {
                const float v = src[(size_t)r * TMAX];
                dst[r * 64 + lane] = (r < lane) ? v : 0.f;   // tau<t mask
            }
        }
        for (int tt = 0; tt < mtv; ++tt) {
            const float2 s = so2[tt];
            const float* Mrow = MT + (size_t)(64 * C + tt) * TMAX + lane;
            #pragma unroll
            for (int K = C + 1; K < 8; ++K) {
                const float mval = Mrow[64 * K];
                hsA[K] = fmaf(s.x, mval, hsA[K]);
                hsB[K] = fmaf(s.y, mval, hsB[K]);
            }
        }
    }
}

__global__ __launch_bounds__(64, 2)
void out_kernel(const float* __restrict__ AT, const float* __restrict__ MT,
                const int* __restrict__ Tp, float* __restrict__ out, int nparts)
{
    const int T = Tp[0];
    const int lane = threadIdx.x;
    const int j = blockIdx.x * 2;
    __shared__ float LD[2 * 4096];
    __shared__ float2 so2[64];

    float hsA[8], hsB[8];
    #pragma unroll
    for (int k = 0; k < 8; ++k) { hsA[k] = 0.f; hsB[k] = 0.f; }
    float vA = REST_F, vB = REST_F;

    {
        const float* src = MT + lane;
        #pragma unroll 16
        for (int r = 0; r < 64; ++r) {
            const float v = src[(size_t)r * TMAX];
            LD[r * 64 + lane] = (r < lane) ? v : 0.f;        // tau<t mask
        }
    }
    out_chunk<0>(AT, MT, hsA, hsB, vA, vB, out, j, lane, T, nparts, LD, so2);
    if (T >  64) out_chunk<1>(AT, MT, hsA, hsB, vA, vB, out, j, lane, T, nparts, LD, so2);
    if (T > 128) out_chunk<2>(AT, MT, hsA, hsB, vA, vB, out, j, lane, T, nparts, LD, so2);
    if (T > 192) out_chunk<3>(AT, MT, hsA, hsB, vA, vB, out, j, lane, T, nparts, LD, so2);
    if (T > 256) out_chunk<4>(AT, MT, hsA, hsB, vA, vB, out, j, lane, T, nparts, LD, so2);
    if (T > 320) out_chunk<5>(AT, MT, hsA, hsB, vA, vB, out, j, lane, T, nparts, LD, so2);
    if (T > 384) out_chunk<6>(AT, MT, hsA, hsB, vA, vB, out, j, lane, T, nparts, LD, so2);
    if (T > 448) out_chunk<7>(AT, MT, hsA, hsB, vA, vB, out, j, lane, T, nparts, LD, so2);
}

extern "C" void kernel_launch(void* const* d_in, const int* in_sizes, int n_in,
                              void* d_out, int out_size, void* d_ws, size_t ws_size,
                              hipStream_t stream) {
    const float* x  = (const float*)d_in[0];
    const float* w1 = (const float*)d_in[1];
    const float* w2 = (const float*)d_in[2];
    const int*   Tp = (const int*)d_in[3];
    float* out = (float*)d_out;
    char* ws = (char*)d_ws;
    // layout: Sfin 1.125M | Sb 64K | G 1M | MT 1M | Sf 2M | AT 8M (or 4M)
    float* Sfin = (float*)(ws);
    unsigned long long* Sb = (unsigned long long*)(ws + 1179648);
    float* G  = (float*)(ws + 1179648 + 65536);
    float* MT = (float*)(ws + 1179648 + 65536 + 1048576);
    float* Sf = (float*)(ws + 1179648 + 65536 + 2 * 1048576);
    float* AT = (float*)(ws + 1179648 + 65536 + 4 * 1048576);
    const size_t need2 = 1179648 + 65536 + 4 * 1048576 + 2 * 4194304;
    const int nparts = (ws_size >= need2) ? 2 : 1;
    const int klen = (nparts == 2) ? 512 : 1024;

    hipLaunchKernelGGL(input_kernel,  dim3(1), dim3(576), 0, stream, x, Tp, Sfin);
    hipLaunchKernelGGL(hidden_kernel, dim3(HID_D / 2), dim3(256), 0, stream, Sfin, w1, Tp, Sf);
    hipLaunchKernelGGL(pack_kernel,   dim3(TMAX), dim3(256), 0, stream, Sf, Tp, Sb);
    hipLaunchKernelGGL(gram_kernel,   dim3(32, 32), dim3(256), 0, stream, Sb, Tp, G);
    hipLaunchKernelGGL(mt_kernel,     dim3(128), dim3(256), 0, stream, G, Tp, MT);
    hipLaunchKernelGGL(gemm_kernel,   dim3(16, 8, nparts), dim3(256), 0, stream,
                       Sf, w2, AT, klen);
    hipLaunchKernelGGL(out_kernel,    dim3(OUT_D / 2), dim3(64), 0, stream, AT, MT, Tp, out, nparts);
}

// Round 10
// 343.183 us; speedup vs baseline: 1.4044x; 1.0755x over previous
//
#include <hip/hip_runtime.h>
#include <stdint.h>

// ---------------------------------------------------------------------------
// Phased SNN:
//   1) hidden raster S: 512 blocks x 256thr; wave = (column, input-half);
//      input LIF recomputed in-register (r7 structure, best measured),
//      manual 2x time-unroll (static parity). 1 barrier/step, 2 waves/SIMD.
//   2) pack S bits + zero tail rows of Sf
//   3+5 merged) gram (G = S S^T popcount) || gemm (A_T = (S@w2_0)^T, K-split)
//      in ONE kernel via disjoint blockIdx ranges (independent inputs)
//   4) M_T via wave-parallel decay scans
//   6) output LIF: 4 cols/block, per-64-chunk LDS M tile + batched GEMV
// Valid because w2 is never clipped -> its evolution is linear in spikes.
// ---------------------------------------------------------------------------

#define DECAY_V  0.90483741803595952f   // exp(-1/10)
#define DECAY_TR 0.95122942450071403f   // exp(-1/20)
#define REST_F   (-70.0f)
#define RESET_F  (-65.0f)
#define THRESH_F (-55.0f)
#define ALPHA_F  (0.95f)
#define BETA_F   (0.8f)
#define NU1_PRE_F  (0.001f)
#define NU1_POST_F (0.01f)
#define NU2_F      (0.0001f)
#define GAIN_F     (20.0f)
#define LOG2D    (-0.072134752044448170f)  // log2(exp(-1/20))

static constexpr int IN_D  = 544;
static constexpr int HID_D = 1024;
static constexpr int OUT_D = 2048;
static constexpr int TMAX  = 512;

#define DP1  0.95122942450071403f
#define DP2  0.90483741803595957f
#define DP4  0.81873075307798186f
#define DP8  0.67032004603563930f
#define DP16 0.44932896411722159f
#define DP32 0.20189651799465541f

__device__ __forceinline__ float rdlane(float x, int l) {
    return __builtin_bit_cast(float,
        __builtin_amdgcn_readlane(__builtin_bit_cast(int, x), l));
}

template <int CTRL>
__device__ __forceinline__ float dpp_add(float x) {
    int y = __builtin_amdgcn_update_dpp(0, __builtin_bit_cast(int, x),
                                        CTRL, 0xF, 0xF, true);
    return x + __builtin_bit_cast(float, y);
}

__device__ __forceinline__ float wave_sum64(float x) {
    x = dpp_add<0xB1>(x);   // quad_perm [1,0,3,2]
    x = dpp_add<0x4E>(x);   // quad_perm [2,3,0,1]
    x = dpp_add<0x114>(x);  // row_shr:4
    x = dpp_add<0x118>(x);  // row_shr:8
    x = dpp_add<0x142>(x);  // row_bcast:15
    x = dpp_add<0x143>(x);  // row_bcast:31
    return rdlane(x, 63);
}

// -------- Phase 1: hidden raster, wave = (column, input-half) --------------
__global__ __launch_bounds__(256, 2)
void hidden_kernel(const float* __restrict__ x, const float* __restrict__ w1,
                   const int* __restrict__ Tp, float* __restrict__ Sf)
{
    const int T = Tp[0];
    const int tid = threadIdx.x, lane = tid & 63, wv = tid >> 6;
    const int cp = wv >> 1;                  // 0/1 -> column within block
    const int h  = wv & 1;                   // input half: [272h, 272h+272)
    const int col = blockIdx.x * 2 + cp;
    const float c0 = REST_F * (1.0f - DECAY_V);
    __shared__ float part[2][4];             // [parity][wave]

    float w[5], vi[5], tr[5], cadd[5];
    #pragma unroll
    for (int k = 0; k < 5; ++k) {
        const int o = 64 * k + lane;         // offset within the half
        const int i = 272 * h + o;
        const bool ok = (o < 272);
        w[k]    = ok ? w1[(size_t)i * HID_D + col] : 0.f;
        cadd[k] = c0 + (ok ? x[i] * GAIN_F : 0.f);
        vi[k]   = REST_F;
        tr[k]   = 0.f;
    }
    float v_h = 0.f, b_h = 0.f, tr_h = 0.f;  // duplicated across the 2 waves
    const bool writer = (h == 0 && lane == 0);

    auto step = [&](int t, int par) {
        float acc = 0.f, s[5];
        #pragma unroll
        for (int k = 0; k < 5; ++k) {        // input LIF for this half
            const float vv = fmaf(DECAY_V, vi[k], cadd[k]);
            const bool sp = (vv >= THRESH_F);
            vi[k] = sp ? RESET_F : vv;
            s[k]  = sp ? 1.f : 0.f;
            tr[k] = fmaxf(tr[k] * DECAY_TR, s[k]);
            acc   = fmaf(s[k], w[k], acc);
        }
        const float p = wave_sum64(acc);
        if (lane == 0) part[par][wv] = p;
        __syncthreads();
        const float tot = p + part[par][wv ^ 1];   // commutative -> bitexact
        const float vh2 = fmaf(ALPHA_F, v_h, tot);
        const bool hp = (vh2 >= 1.0f + b_h);
        const float sh = hp ? 1.f : 0.f;
        v_h  = hp ? 0.f : vh2;
        b_h  = fmaf(BETA_F, b_h, sh);
        tr_h = hp ? 1.f : tr_h * DECAY_TR;
        const float apot = hp ? NU1_POST_F : 0.f;
        const float adep = NU1_PRE_F * tr_h;
        #pragma unroll
        for (int k = 0; k < 5; ++k) {
            const float a  = fmaf(apot, tr[k], w[k]);
            const float nw = fmaf(-adep, s[k], a);
            w[k] = __builtin_amdgcn_fmed3f(nw, 0.f, 1.f);
        }
        if (writer) Sf[(size_t)t * HID_D + col] = sh;
    };

    int t = 0;
    for (; t + 1 < T; t += 2) {              // static parity, no per-step calc
        step(t, 0);
        step(t + 1, 1);
    }
    if (t < T) step(t, 0);
}

// ---------------- Phase 2: bit-pack S (+ zero tail rows) -------------------
__global__ void pack_kernel(float* __restrict__ Sf, const int* __restrict__ Tp,
                            unsigned long long* __restrict__ Sb)
{
    const int T = Tp[0];
    const int t = blockIdx.x;
    const int lane = threadIdx.x & 63, wv = threadIdx.x >> 6;
    if (t >= T) {
        ((float4*)(Sf + (size_t)t * HID_D))[threadIdx.x] = make_float4(0.f, 0.f, 0.f, 0.f);
        return;
    }
    #pragma unroll
    for (int q = 0; q < 4; ++q) {
        const int word = wv * 4 + q;
        const float s = Sf[(size_t)t * HID_D + word * 64 + lane];
        const unsigned long long m = __ballot(s > 0.5f);
        if (lane == 0) Sb[(size_t)t * 16 + word] = m;
    }
}

// -------- Phases 3+5 merged: gram (blocks 0..1023) | gemm (rest) -----------
__global__ __launch_bounds__(256)
void gramgemm_kernel(const unsigned long long* __restrict__ Sb,
                     const int* __restrict__ Tp, float* __restrict__ G,
                     const float* __restrict__ Sf, const float* __restrict__ w2,
                     float* __restrict__ AT, int klen)
{
    __shared__ __align__(16) char smem[16640];
    const int b = blockIdx.x, tid = threadIdx.x;
    if (b < 1024) {
        // ------------------------- gram: G = S S^T --------------------------
        const int by = b >> 5, bx = b & 31;
        if (bx > by) return;
        const int T = Tp[0];
        typedef unsigned long long u64;
        u64 (*tR)[17] = (u64(*)[17])(smem);
        u64 (*uR)[17] = (u64(*)[17])(smem + 2176);
        {
            const int r = tid >> 4, w0 = tid & 15;
            const int trow = by * 16 + r, urow = bx * 16 + r;
            tR[r][w0] = (trow < T) ? Sb[(size_t)trow * 16 + w0] : 0ULL;
            uR[r][w0] = (urow < T) ? Sb[(size_t)urow * 16 + w0] : 0ULL;
        }
        __syncthreads();
        const int tx = tid & 15, ty = tid >> 4;
        const int t = by * 16 + ty, u = bx * 16 + tx;
        if (t < T && u < t) {
            int s = 0;
            #pragma unroll
            for (int w0 = 0; w0 < 16; ++w0) s += __popcll(tR[ty][w0] & uR[tx][w0]);
            G[(size_t)t * TMAX + u] = (float)s;
        }
    } else {
        // --------------------- gemm: A_T = (S @ w2)^T -----------------------
        const int g = b - 1024;
        const int z = g >> 7, r = g & 127;
        const int j0 = (r & 15) * 128, t0 = (r >> 4) * 64;
        const int kbase = z * klen;
        float (*Ss)[68]  = (float(*)[68])(smem);          // 4352 B
        float (*Ws)[192] = (float(*)[192])(smem + 4352);  // 12288 B
        const int sr = tid >> 2, sq = tid & 3;
        const int wq2 = tid & 31, wr2 = tid >> 5;
        const int wcol = (wq2 >> 1) * 12 + (wq2 & 1) * 4;
        const int tj = tid & 15, tt = tid >> 4;
        const int tjc = tj * 12;

        float acc[4][8];
        #pragma unroll
        for (int a = 0; a < 4; ++a)
            #pragma unroll
            for (int bb = 0; bb < 8; ++bb) acc[a][bb] = 0.f;

        for (int k0 = 0; k0 < klen; k0 += 16) {
            const float4 sv = *(const float4*)&Sf[(size_t)(t0 + sr) * HID_D + kbase + k0 + sq * 4];
            const float4 wa = *(const float4*)&w2[(size_t)(kbase + k0 + wr2) * OUT_D + j0 + wq2 * 4];
            const float4 wb = *(const float4*)&w2[(size_t)(kbase + k0 + wr2 + 8) * OUT_D + j0 + wq2 * 4];
            __syncthreads();
            Ss[sq * 4 + 0][sr] = sv.x;
            Ss[sq * 4 + 1][sr] = sv.y;
            Ss[sq * 4 + 2][sr] = sv.z;
            Ss[sq * 4 + 3][sr] = sv.w;
            *(float4*)&Ws[wr2][wcol] = wa;
            *(float4*)&Ws[wr2 + 8][wcol] = wb;
            __syncthreads();
            #pragma unroll
            for (int kk = 0; kk < 16; ++kk) {
                const float4 a4 = *(const float4*)&Ss[kk][tt * 4];
                const float4 b0 = *(const float4*)&Ws[kk][tjc];
                const float4 b1 = *(const float4*)&Ws[kk][tjc + 4];
                const float aa[4] = {a4.x, a4.y, a4.z, a4.w};
                const float bbv[8] = {b0.x, b0.y, b0.z, b0.w, b1.x, b1.y, b1.z, b1.w};
                #pragma unroll
                for (int ti = 0; ti < 4; ++ti)
                    #pragma unroll
                    for (int jj = 0; jj < 8; ++jj)
                        acc[ti][jj] = fmaf(aa[ti], bbv[jj], acc[ti][jj]);
            }
        }
        #pragma unroll
        for (int jj = 0; jj < 8; ++jj)
            *(float4*)&AT[(size_t)z * OUT_D * TMAX +
                          (size_t)(j0 + tj * 8 + jj) * TMAX + t0 + tt * 4] =
                make_float4(acc[0][jj], acc[1][jj], acc[2][jj], acc[3][jj]);
    }
}

// -------------- Phase 4: M_T columns via parallel decay scans --------------
__global__ __launch_bounds__(256)
void mt_kernel(const float* __restrict__ G, const int* __restrict__ Tp,
               float* __restrict__ MT)
{
    const int T = Tp[0];
    const int lane = threadIdx.x & 63;
    const int t = blockIdx.x * 4 + (threadIdx.x >> 6);
    if (t >= T) return;
    const float* Gr = G + (size_t)t * TMAX;
    const float dl1  = exp2f((float)(lane + 1) * LOG2D);
    const float d64l = exp2f((float)(64 - lane) * LOG2D);

    float g[8], kk[8];
    #pragma unroll
    for (int c = 0; c < 8; ++c) {
        const int tau = 64 * c + lane;
        g[c] = (tau < t) ? Gr[tau] : 0.f;
    }
    float kc = 0.f;
    #pragma unroll
    for (int c = 7; c >= 0; --c) {
        float k = g[c], u;
        u = __shfl_down(k, 1, 64);  if (lane < 63) k = fmaf(DP1, u, k);
        u = __shfl_down(k, 2, 64);  if (lane < 62) k = fmaf(DP2, u, k);
        u = __shfl_down(k, 4, 64);  if (lane < 60) k = fmaf(DP4, u, k);
        u = __shfl_down(k, 8, 64);  if (lane < 56) k = fmaf(DP8, u, k);
        u = __shfl_down(k, 16, 64); if (lane < 48) k = fmaf(DP16, u, k);
        u = __shfl_down(k, 32, 64); if (lane < 32) k = fmaf(DP32, u, k);
        k = fmaf(d64l, kc, k);
        kk[c] = k;
        kc = rdlane(k, 0);
    }
    float hc = 0.f;
    #pragma unroll
    for (int c = 0; c < 8; ++c) {
        float h = g[c], u;
        u = __shfl_up(h, 1, 64);  if (lane >= 1)  h = fmaf(DP1, u, h);
        u = __shfl_up(h, 2, 64);  if (lane >= 2)  h = fmaf(DP2, u, h);
        u = __shfl_up(h, 4, 64);  if (lane >= 4)  h = fmaf(DP4, u, h);
        u = __shfl_up(h, 8, 64);  if (lane >= 8)  h = fmaf(DP8, u, h);
        u = __shfl_up(h, 16, 64); if (lane >= 16) h = fmaf(DP16, u, h);
        u = __shfl_up(h, 32, 64); if (lane >= 32) h = fmaf(DP32, u, h);
        h = fmaf(dl1, hc, h);
        const int tau = 64 * c + lane;
        if (tau < t) MT[(size_t)tau * TMAX + t] = NU2_F * (h - kk[c]);
        hc = rdlane(h, 63);
    }
}

// -------------- Phase 6: output recurrence, 4 cols per block ---------------
template <int C>
__device__ __forceinline__ void out_chunk(
    const float* __restrict__ AT, const float* __restrict__ MT,
    float (&hs)[4][8], float (&v)[4],
    float* __restrict__ out, int j, int lane, int T, int nparts,
    float* __restrict__ LD, float4* __restrict__ so4)
{
    const int rem = T - 64 * C;
    const int mtv = (rem < 64) ? rem : 64;
    float av[4];
    #pragma unroll
    for (int q = 0; q < 4; ++q) {
        float a = AT[(size_t)(j + q) * TMAX + 64 * C + lane];
        for (int p = 1; p < nparts; ++p)    // ascending p: fixed sum order
            a += AT[(size_t)p * OUT_D * TMAX + (size_t)(j + q) * TMAX + 64 * C + lane];
        av[q] = a;
    }
    const float* ldb = LD + (C & 1) * 4096;
    float acc[4];
    #pragma unroll
    for (int q = 0; q < 4; ++q) acc[q] = hs[q][C];
    float mv0 = ldb[lane];
    float mv1 = (mtv > 1) ? ldb[64 + lane] : 0.f;
    for (int tt = 0; tt < mtv; ++tt) {
        const float mv = mv0;
        mv0 = mv1;
        if (tt + 2 < mtv) mv1 = ldb[(tt + 2) * 64 + lane];
        float so[4];
        #pragma unroll
        for (int q = 0; q < 4; ++q) {
            const float iv = rdlane(av[q] + acc[q], tt);
            const float vd = fmaf(DECAY_V, v[q], REST_F * (1.0f - DECAY_V)) + iv;
            const bool sp = (vd >= THRESH_F);
            so[q] = sp ? 1.f : 0.f;
            v[q]  = sp ? RESET_F : vd;
        }
        if (lane == 0)
            *(float4*)&out[(size_t)(64 * C + tt) * OUT_D + j] =
                make_float4(so[0], so[1], so[2], so[3]);
        if (lane == tt) so4[tt] = make_float4(so[0], so[1], so[2], so[3]);
        #pragma unroll
        for (int q = 0; q < 4; ++q) acc[q] = fmaf(so[q], mv, acc[q]);
    }
    if (C + 1 < 8 && 64 * (C + 1) < T) {
        {   // stage next chunk's diagonal tile (tau<t masked)
            float* dst = LD + ((C + 1) & 1) * 4096;
            const float* src = MT + (size_t)(64 * (C + 1)) * TMAX + 64 * (C + 1) + lane;
            #pragma unroll 16
            for (int rr = 0; rr < 64; ++rr) {
                const float vv = src[(size_t)rr * TMAX];
                dst[rr * 64 + lane] = (rr < lane) ? vv : 0.f;
            }
        }
        // batched GEMV into future chunks' hs (ascending tt -> bitexact order)
        for (int tt = 0; tt < mtv; ++tt) {
            const float4 s = so4[tt];
            const float* Mrow = MT + (size_t)(64 * C + tt) * TMAX + lane;
            #pragma unroll
            for (int K = C + 1; K < 8; ++K) {
                const float mval = Mrow[64 * K];
                hs[0][K] = fmaf(s.x, mval, hs[0][K]);
                hs[1][K] = fmaf(s.y, mval, hs[1][K]);
                hs[2][K] = fmaf(s.z, mval, hs[2][K]);
                hs[3][K] = fmaf(s.w, mval, hs[3][K]);
            }
        }
    }
}

__global__ __launch_bounds__(64, 2)
void out_kernel(const float* __restrict__ AT, const float* __restrict__ MT,
                const int* __restrict__ Tp, float* __restrict__ out, int nparts)
{
    const int T = Tp[0];
    const int lane = threadIdx.x;
    const int j = blockIdx.x * 4;            // 512 blocks, 4 cols each
    __shared__ float LD[2 * 4096];
    __shared__ float4 so4[64];

    float hs[4][8];
    #pragma unroll
    for (int q = 0; q < 4; ++q)
        #pragma unroll
        for (int k = 0; k < 8; ++k) hs[q][k] = 0.f;
    float v[4] = {REST_F, REST_F, REST_F, REST_F};

    {   // stage chunk 0
        const float* src = MT + lane;
        #pragma unroll 16
        for (int rr = 0; rr < 64; ++rr) {
            const float vv = src[(size_t)rr * TMAX];
            LD[rr * 64 + lane] = (rr < lane) ? vv : 0.f;
        }
    }
    out_chunk<0>(AT, MT, hs, v, out, j, lane, T, nparts, LD, so4);
    if (T >  64) out_chunk<1>(AT, MT, hs, v, out, j, lane, T, nparts, LD, so4);
    if (T > 128) out_chunk<2>(AT, MT, hs, v, out, j, lane, T, nparts, LD, so4);
    if (T > 192) out_chunk<3>(AT, MT, hs, v, out, j, lane, T, nparts, LD, so4);
    if (T > 256) out_chunk<4>(AT, MT, hs, v, out, j, lane, T, nparts, LD, so4);
    if (T > 320) out_chunk<5>(AT, MT, hs, v, out, j, lane, T, nparts, LD, so4);
    if (T > 384) out_chunk<6>(AT, MT, hs, v, out, j, lane, T, nparts, LD, so4);
    if (T > 448) out_chunk<7>(AT, MT, hs, v, out, j, lane, T, nparts, LD, so4);
}

extern "C" void kernel_launch(void* const* d_in, const int* in_sizes, int n_in,
                              void* d_out, int out_size, void* d_ws, size_t ws_size,
                              hipStream_t stream) {
    const float* x  = (const float*)d_in[0];
    const float* w1 = (const float*)d_in[1];
    const float* w2 = (const float*)d_in[2];
    const int*   Tp = (const int*)d_in[3];
    float* out = (float*)d_out;
    char* ws = (char*)d_ws;
    // layout: Sb 64K | G 1M | MT 1M | Sf 2M | AT nparts*4M
    unsigned long long* Sb = (unsigned long long*)(ws);
    float* G  = (float*)(ws + 65536);
    float* MT = (float*)(ws + 65536 + 1048576);
    float* Sf = (float*)(ws + 65536 + 2 * 1048576);
    float* AT = (float*)(ws + 65536 + 4 * 1048576);
    const size_t base  = 65536 + 4 * 1048576;
    const int nparts = (ws_size >= base + 4 * 4194304) ? 4
                     : (ws_size >= base + 2 * 4194304) ? 2 : 1;
    const int klen = 1024 / nparts;

    hipLaunchKernelGGL(hidden_kernel, dim3(HID_D / 2), dim3(256), 0, stream, x, w1, Tp, Sf);
    hipLaunchKernelGGL(pack_kernel,   dim3(TMAX), dim3(256), 0, stream, Sf, Tp, Sb);
    hipLaunchKernelGGL(gramgemm_kernel, dim3(1024 + 128 * nparts), dim3(256), 0, stream,
                       Sb, Tp, G, Sf, w2, AT, klen);
    hipLaunchKernelGGL(mt_kernel,     dim3(128), dim3(256), 0, stream, G, Tp, MT);
    hipLaunchKernelGGL(out_kernel,    dim3(OUT_D / 4), dim3(64), 0, stream, AT, MT, Tp, out, nparts);
}

// Round 11
// 275.365 us; speedup vs baseline: 1.7503x; 1.2463x over previous
//
#include <hip/hip_runtime.h>
#include <stdint.h>

// ---------------------------------------------------------------------------
// Phased SNN:
//   1) hidden raster S: 512 blocks x 256thr; wave = (column, input-half);
//      input LIF recomputed in-register; 1 barrier/step, 2 waves/SIMD.
//   2) pack S bits + zero tail rows of Sf
//   3+5 merged) gram (G = S S^T popcount) || gemm (A_T = (S@w2_0)^T, K-split)
//   4) M_T via wave-parallel decay scans
//   6) output LIF v3: 4 waves/block, 1 col/wave; so-history in a register;
//      static-bound unrolled GEMV (pipelined loads); cooperative tile staging.
// Valid because w2 is never clipped -> its evolution is linear in spikes.
// ---------------------------------------------------------------------------

#define DECAY_V  0.90483741803595952f   // exp(-1/10)
#define DECAY_TR 0.95122942450071403f   // exp(-1/20)
#define REST_F   (-70.0f)
#define RESET_F  (-65.0f)
#define THRESH_F (-55.0f)
#define ALPHA_F  (0.95f)
#define BETA_F   (0.8f)
#define NU1_PRE_F  (0.001f)
#define NU1_POST_F (0.01f)
#define NU2_F      (0.0001f)
#define GAIN_F     (20.0f)
#define LOG2D    (-0.072134752044448170f)  // log2(exp(-1/20))

static constexpr int IN_D  = 544;
static constexpr int HID_D = 1024;
static constexpr int OUT_D = 2048;
static constexpr int TMAX  = 512;

#define DP1  0.95122942450071403f
#define DP2  0.90483741803595957f
#define DP4  0.81873075307798186f
#define DP8  0.67032004603563930f
#define DP16 0.44932896411722159f
#define DP32 0.20189651799465541f

__device__ __forceinline__ float rdlane(float x, int l) {
    return __builtin_bit_cast(float,
        __builtin_amdgcn_readlane(__builtin_bit_cast(int, x), l));
}

template <int CTRL>
__device__ __forceinline__ float dpp_add(float x) {
    int y = __builtin_amdgcn_update_dpp(0, __builtin_bit_cast(int, x),
                                        CTRL, 0xF, 0xF, true);
    return x + __builtin_bit_cast(float, y);
}

__device__ __forceinline__ float wave_sum64(float x) {
    x = dpp_add<0xB1>(x);   // quad_perm [1,0,3,2]
    x = dpp_add<0x4E>(x);   // quad_perm [2,3,0,1]
    x = dpp_add<0x114>(x);  // row_shr:4
    x = dpp_add<0x118>(x);  // row_shr:8
    x = dpp_add<0x142>(x);  // row_bcast:15
    x = dpp_add<0x143>(x);  // row_bcast:31
    return rdlane(x, 63);
}

// -------- Phase 1: hidden raster, wave = (column, input-half) --------------
__global__ __launch_bounds__(256, 2)
void hidden_kernel(const float* __restrict__ x, const float* __restrict__ w1,
                   const int* __restrict__ Tp, float* __restrict__ Sf)
{
    const int T = Tp[0];
    const int tid = threadIdx.x, lane = tid & 63, wv = tid >> 6;
    const int cp = wv >> 1;                  // 0/1 -> column within block
    const int h  = wv & 1;                   // input half: [272h, 272h+272)
    const int col = blockIdx.x * 2 + cp;
    const float c0 = REST_F * (1.0f - DECAY_V);
    __shared__ float part[2][4];             // [parity][wave]

    float w[5], vi[5], tr[5], cadd[5];
    #pragma unroll
    for (int k = 0; k < 5; ++k) {
        const int o = 64 * k + lane;         // offset within the half
        const int i = 272 * h + o;
        const bool ok = (o < 272);
        w[k]    = ok ? w1[(size_t)i * HID_D + col] : 0.f;
        cadd[k] = c0 + (ok ? x[i] * GAIN_F : 0.f);
        vi[k]   = REST_F;
        tr[k]   = 0.f;
    }
    float v_h = 0.f, b_h = 0.f, tr_h = 0.f;  // duplicated across the 2 waves
    const bool writer = (h == 0 && lane == 0);

    auto step = [&](int t, int par) {
        float acc = 0.f, s[5];
        #pragma unroll
        for (int k = 0; k < 5; ++k) {        // input LIF for this half
            const float vv = fmaf(DECAY_V, vi[k], cadd[k]);
            const bool sp = (vv >= THRESH_F);
            vi[k] = sp ? RESET_F : vv;
            s[k]  = sp ? 1.f : 0.f;
            tr[k] = fmaxf(tr[k] * DECAY_TR, s[k]);
            acc   = fmaf(s[k], w[k], acc);
        }
        const float p = wave_sum64(acc);
        if (lane == 0) part[par][wv] = p;
        __syncthreads();
        const float tot = p + part[par][wv ^ 1];   // commutative -> bitexact
        const float vh2 = fmaf(ALPHA_F, v_h, tot);
        const bool hp = (vh2 >= 1.0f + b_h);
        const float sh = hp ? 1.f : 0.f;
        v_h  = hp ? 0.f : vh2;
        b_h  = fmaf(BETA_F, b_h, sh);
        tr_h = hp ? 1.f : tr_h * DECAY_TR;
        const float apot = hp ? NU1_POST_F : 0.f;
        const float adep = NU1_PRE_F * tr_h;
        #pragma unroll
        for (int k = 0; k < 5; ++k) {
            const float a  = fmaf(apot, tr[k], w[k]);
            const float nw = fmaf(-adep, s[k], a);
            w[k] = __builtin_amdgcn_fmed3f(nw, 0.f, 1.f);
        }
        if (writer) Sf[(size_t)t * HID_D + col] = sh;
    };

    int t = 0;
    for (; t + 1 < T; t += 2) {              // static parity
        step(t, 0);
        step(t + 1, 1);
    }
    if (t < T) step(t, 0);
}

// ---------------- Phase 2: bit-pack S (+ zero tail rows) -------------------
__global__ void pack_kernel(float* __restrict__ Sf, const int* __restrict__ Tp,
                            unsigned long long* __restrict__ Sb)
{
    const int T = Tp[0];
    const int t = blockIdx.x;
    const int lane = threadIdx.x & 63, wv = threadIdx.x >> 6;
    if (t >= T) {
        ((float4*)(Sf + (size_t)t * HID_D))[threadIdx.x] = make_float4(0.f, 0.f, 0.f, 0.f);
        return;
    }
    #pragma unroll
    for (int q = 0; q < 4; ++q) {
        const int word = wv * 4 + q;
        const float s = Sf[(size_t)t * HID_D + word * 64 + lane];
        const unsigned long long m = __ballot(s > 0.5f);
        if (lane == 0) Sb[(size_t)t * 16 + word] = m;
    }
}

// -------- Phases 3+5 merged: gram (blocks 0..1023) | gemm (rest) -----------
__global__ __launch_bounds__(256)
void gramgemm_kernel(const unsigned long long* __restrict__ Sb,
                     const int* __restrict__ Tp, float* __restrict__ G,
                     const float* __restrict__ Sf, const float* __restrict__ w2,
                     float* __restrict__ AT, int klen)
{
    __shared__ __align__(16) char smem[16640];
    const int b = blockIdx.x, tid = threadIdx.x;
    if (b < 1024) {
        const int by = b >> 5, bx = b & 31;
        if (bx > by) return;
        const int T = Tp[0];
        typedef unsigned long long u64;
        u64 (*tR)[17] = (u64(*)[17])(smem);
        u64 (*uR)[17] = (u64(*)[17])(smem + 2176);
        {
            const int r = tid >> 4, w0 = tid & 15;
            const int trow = by * 16 + r, urow = bx * 16 + r;
            tR[r][w0] = (trow < T) ? Sb[(size_t)trow * 16 + w0] : 0ULL;
            uR[r][w0] = (urow < T) ? Sb[(size_t)urow * 16 + w0] : 0ULL;
        }
        __syncthreads();
        const int tx = tid & 15, ty = tid >> 4;
        const int t = by * 16 + ty, u = bx * 16 + tx;
        if (t < T && u < t) {
            int s = 0;
            #pragma unroll
            for (int w0 = 0; w0 < 16; ++w0) s += __popcll(tR[ty][w0] & uR[tx][w0]);
            G[(size_t)t * TMAX + u] = (float)s;
        }
    } else {
        const int g = b - 1024;
        const int z = g >> 7, r = g & 127;
        const int j0 = (r & 15) * 128, t0 = (r >> 4) * 64;
        const int kbase = z * klen;
        float (*Ss)[68]  = (float(*)[68])(smem);
        float (*Ws)[192] = (float(*)[192])(smem + 4352);
        const int sr = tid >> 2, sq = tid & 3;
        const int wq2 = tid & 31, wr2 = tid >> 5;
        const int wcol = (wq2 >> 1) * 12 + (wq2 & 1) * 4;
        const int tj = tid & 15, tt = tid >> 4;
        const int tjc = tj * 12;

        float acc[4][8];
        #pragma unroll
        for (int a = 0; a < 4; ++a)
            #pragma unroll
            for (int bb = 0; bb < 8; ++bb) acc[a][bb] = 0.f;

        for (int k0 = 0; k0 < klen; k0 += 16) {
            const float4 sv = *(const float4*)&Sf[(size_t)(t0 + sr) * HID_D + kbase + k0 + sq * 4];
            const float4 wa = *(const float4*)&w2[(size_t)(kbase + k0 + wr2) * OUT_D + j0 + wq2 * 4];
            const float4 wb = *(const float4*)&w2[(size_t)(kbase + k0 + wr2 + 8) * OUT_D + j0 + wq2 * 4];
            __syncthreads();
            Ss[sq * 4 + 0][sr] = sv.x;
            Ss[sq * 4 + 1][sr] = sv.y;
            Ss[sq * 4 + 2][sr] = sv.z;
            Ss[sq * 4 + 3][sr] = sv.w;
            *(float4*)&Ws[wr2][wcol] = wa;
            *(float4*)&Ws[wr2 + 8][wcol] = wb;
            __syncthreads();
            #pragma unroll
            for (int kk = 0; kk < 16; ++kk) {
                const float4 a4 = *(const float4*)&Ss[kk][tt * 4];
                const float4 b0 = *(const float4*)&Ws[kk][tjc];
                const float4 b1 = *(const float4*)&Ws[kk][tjc + 4];
                const float aa[4] = {a4.x, a4.y, a4.z, a4.w};
                const float bbv[8] = {b0.x, b0.y, b0.z, b0.w, b1.x, b1.y, b1.z, b1.w};
                #pragma unroll
                for (int ti = 0; ti < 4; ++ti)
                    #pragma unroll
                    for (int jj = 0; jj < 8; ++jj)
                        acc[ti][jj] = fmaf(aa[ti], bbv[jj], acc[ti][jj]);
            }
        }
        #pragma unroll
        for (int jj = 0; jj < 8; ++jj)
            *(float4*)&AT[(size_t)z * OUT_D * TMAX +
                          (size_t)(j0 + tj * 8 + jj) * TMAX + t0 + tt * 4] =
                make_float4(acc[0][jj], acc[1][jj], acc[2][jj], acc[3][jj]);
    }
}

// -------------- Phase 4: M_T columns via parallel decay scans --------------
__global__ __launch_bounds__(256)
void mt_kernel(const float* __restrict__ G, const int* __restrict__ Tp,
               float* __restrict__ MT)
{
    const int T = Tp[0];
    const int lane = threadIdx.x & 63;
    const int t = blockIdx.x * 4 + (threadIdx.x >> 6);
    if (t >= T) return;
    const float* Gr = G + (size_t)t * TMAX;
    const float dl1  = exp2f((float)(lane + 1) * LOG2D);
    const float d64l = exp2f((float)(64 - lane) * LOG2D);

    float g[8], kk[8];
    #pragma unroll
    for (int c = 0; c < 8; ++c) {
        const int tau = 64 * c + lane;
        g[c] = (tau < t) ? Gr[tau] : 0.f;
    }
    float kc = 0.f;
    #pragma unroll
    for (int c = 7; c >= 0; --c) {
        float k = g[c], u;
        u = __shfl_down(k, 1, 64);  if (lane < 63) k = fmaf(DP1, u, k);
        u = __shfl_down(k, 2, 64);  if (lane < 62) k = fmaf(DP2, u, k);
        u = __shfl_down(k, 4, 64);  if (lane < 60) k = fmaf(DP4, u, k);
        u = __shfl_down(k, 8, 64);  if (lane < 56) k = fmaf(DP8, u, k);
        u = __shfl_down(k, 16, 64); if (lane < 48) k = fmaf(DP16, u, k);
        u = __shfl_down(k, 32, 64); if (lane < 32) k = fmaf(DP32, u, k);
        k = fmaf(d64l, kc, k);
        kk[c] = k;
        kc = rdlane(k, 0);
    }
    float hc = 0.f;
    #pragma unroll
    for (int c = 0; c < 8; ++c) {
        float h = g[c], u;
        u = __shfl_up(h, 1, 64);  if (lane >= 1)  h = fmaf(DP1, u, h);
        u = __shfl_up(h, 2, 64);  if (lane >= 2)  h = fmaf(DP2, u, h);
        u = __shfl_up(h, 4, 64);  if (lane >= 4)  h = fmaf(DP4, u, h);
        u = __shfl_up(h, 8, 64);  if (lane >= 8)  h = fmaf(DP8, u, h);
        u = __shfl_up(h, 16, 64); if (lane >= 16) h = fmaf(DP16, u, h);
        u = __shfl_up(h, 32, 64); if (lane >= 32) h = fmaf(DP32, u, h);
        h = fmaf(dl1, hc, h);
        const int tau = 64 * c + lane;
        if (tau < t) MT[(size_t)tau * TMAX + t] = NU2_F * (h - kk[c]);
        hc = rdlane(h, 63);
    }
}

// ------- Phase 6 v3: output recurrence, 1 col/wave, 4 waves/block ----------
template <int C>
__device__ __forceinline__ void out_chunk(
    const float* __restrict__ AT, const float* __restrict__ MT,
    float (&hs)[8], float& v, float* __restrict__ out,
    int j, int lane, int w, int T, int nparts, float* __restrict__ LD)
{
    __syncthreads();   // prev chunk's tile reads done; this chunk's tile ready
    constexpr int t0 = 64 * C;
    const int rem = T - t0;
    const int mtv = (rem < 64) ? rem : 64;
    float av = AT[(size_t)j * TMAX + t0 + lane];
    #pragma unroll
    for (int p = 1; p < 4; ++p)                 // ascending p: fixed sum order
        if (p < nparts)
            av += AT[(size_t)p * OUT_D * TMAX + (size_t)j * TMAX + t0 + lane];
    const bool hasNext = (C + 1 < 8) && (64 * (C + 1) < T);
    if (hasNext) {   // stage NEXT chunk's diagonal tile early (16 rows/wave)
        float* dst = LD + ((C + 1) & 1) * 4096;
        const float* src = MT + (size_t)(64 * (C + 1)) * TMAX + 64 * (C + 1) + lane;
        #pragma unroll
        for (int rr = 0; rr < 16; ++rr) {
            const int r = w * 16 + rr;
            const float vv = src[(size_t)r * TMAX];
            dst[r * 64 + lane] = (r < lane) ? vv : 0.f;      // tau<t mask
        }
    }
    const float* ldb = LD + (C & 1) * 4096;
    const float cc = REST_F * (1.0f - DECAY_V);
    float acc = hs[C];
    float sreg = 0.f;   // lane tt keeps so(t0+tt)

    auto sstep = [&](int tt, float& m, int reload) {
        const float iv = rdlane(av + acc, tt);
        const float vd = fmaf(DECAY_V, v, cc) + iv;
        const bool sp = (vd >= THRESH_F);
        const float so = sp ? 1.f : 0.f;        // wave-uniform
        v = sp ? RESET_F : vd;
        sreg = (lane == tt) ? so : sreg;
        acc = fmaf(so, m, acc);
        if (reload < 64) m = ldb[reload * 64 + lane];
    };

    if (rem >= 64) {                            // static path, 4-deep LDS ring
        float m0 = ldb[lane], m1 = ldb[64 + lane],
              m2 = ldb[128 + lane], m3 = ldb[192 + lane];
        #pragma unroll 1
        for (int tt = 0; tt < 64; tt += 4) {
            sstep(tt,     m0, tt + 4);
            sstep(tt + 1, m1, tt + 5);
            sstep(tt + 2, m2, tt + 6);
            sstep(tt + 3, m3, tt + 7);
        }
    } else {                                    // tail chunk, dynamic bound
        float m0 = ldb[lane];
        float m1 = (mtv > 1) ? ldb[64 + lane] : 0.f;
        for (int tt = 0; tt < mtv; ++tt) {
            const float mv = m0;
            m0 = m1;
            if (tt + 2 < mtv) m1 = ldb[(tt + 2) * 64 + lane];
            const float iv = rdlane(av + acc, tt);
            const float vd = fmaf(DECAY_V, v, cc) + iv;
            const bool sp = (vd >= THRESH_F);
            const float so = sp ? 1.f : 0.f;
            v = sp ? RESET_F : vd;
            sreg = (lane == tt) ? so : sreg;
            acc = fmaf(so, mv, acc);
        }
    }
    if (lane < mtv) out[(size_t)(t0 + lane) * OUT_D + j] = sreg;

    if (hasNext) {   // batched scatter into future chunks (ascending tt per K)
        #pragma unroll 4
        for (int tt = 0; tt < 64; ++tt) {
            const float s = rdlane(sreg, tt);
            const float* Mrow = MT + (size_t)(t0 + tt) * TMAX + lane;
            #pragma unroll
            for (int K = C + 1; K < 8; ++K)
                hs[K] = fmaf(s, Mrow[64 * K], hs[K]);
        }
    }
}

__global__ __launch_bounds__(256, 2)
void out_kernel(const float* __restrict__ AT, const float* __restrict__ MT,
                const int* __restrict__ Tp, float* __restrict__ out, int nparts)
{
    const int T = Tp[0];
    const int tid = threadIdx.x, lane = tid & 63, w = tid >> 6;
    const int j = blockIdx.x * 4 + w;           // 512 blocks, 1 col per wave
    __shared__ float LD[2 * 4096];

    float hs[8];
    #pragma unroll
    for (int k = 0; k < 8; ++k) hs[k] = 0.f;
    float v = REST_F;

    {   // stage chunk 0 tile (cooperative)
        const float* src = MT + lane;
        #pragma unroll
        for (int rr = 0; rr < 16; ++rr) {
            const int r = w * 16 + rr;
            const float vv = src[(size_t)r * TMAX];
            LD[r * 64 + lane] = (r < lane) ? vv : 0.f;
        }
    }
    out_chunk<0>(AT, MT, hs, v, out, j, lane, w, T, nparts, LD);
    if (T >  64) out_chunk<1>(AT, MT, hs, v, out, j, lane, w, T, nparts, LD);
    if (T > 128) out_chunk<2>(AT, MT, hs, v, out, j, lane, w, T, nparts, LD);
    if (T > 192) out_chunk<3>(AT, MT, hs, v, out, j, lane, w, T, nparts, LD);
    if (T > 256) out_chunk<4>(AT, MT, hs, v, out, j, lane, w, T, nparts, LD);
    if (T > 320) out_chunk<5>(AT, MT, hs, v, out, j, lane, w, T, nparts, LD);
    if (T > 384) out_chunk<6>(AT, MT, hs, v, out, j, lane, w, T, nparts, LD);
    if (T > 448) out_chunk<7>(AT, MT, hs, v, out, j, lane, w, T, nparts, LD);
}

extern "C" void kernel_launch(void* const* d_in, const int* in_sizes, int n_in,
                              void* d_out, int out_size, void* d_ws, size_t ws_size,
                              hipStream_t stream) {
    const float* x  = (const float*)d_in[0];
    const float* w1 = (const float*)d_in[1];
    const float* w2 = (const float*)d_in[2];
    const int*   Tp = (const int*)d_in[3];
    float* out = (float*)d_out;
    char* ws = (char*)d_ws;
    // layout: Sb 64K | G 1M | MT 1M | Sf 2M | AT nparts*4M
    unsigned long long* Sb = (unsigned long long*)(ws);
    float* G  = (float*)(ws + 65536);
    float* MT = (float*)(ws + 65536 + 1048576);
    float* Sf = (float*)(ws + 65536 + 2 * 1048576);
    float* AT = (float*)(ws + 65536 + 4 * 1048576);
    const size_t base  = 65536 + 4 * 1048576;
    const int nparts = (ws_size >= base + 4 * 4194304) ? 4
                     : (ws_size >= base + 2 * 4194304) ? 2 : 1;
    const int klen = 1024 / nparts;

    hipLaunchKernelGGL(hidden_kernel, dim3(HID_D / 2), dim3(256), 0, stream, x, w1, Tp, Sf);
    hipLaunchKernelGGL(pack_kernel,   dim3(TMAX), dim3(256), 0, stream, Sf, Tp, Sb);
    hipLaunchKernelGGL(gramgemm_kernel, dim3(1024 + 128 * nparts), dim3(256), 0, stream,
                       Sb, Tp, G, Sf, w2, AT, klen);
    hipLaunchKernelGGL(mt_kernel,     dim3(128), dim3(256), 0, stream, G, Tp, MT);
    hipLaunchKernelGGL(out_kernel,    dim3(OUT_D / 4), dim3(256), 0, stream, AT, MT, Tp, out, nparts);
}